// Round 12
// baseline (138.308 us; speedup 1.0000x reference)
//
#include <hip/hip_runtime.h>

typedef unsigned int u32;
typedef unsigned short u16;
typedef __attribute__((ext_vector_type(8))) short short8;
typedef __attribute__((ext_vector_type(4))) float f32x4;
typedef __attribute__((ext_vector_type(2))) u32 u32x2;
typedef __attribute__((ext_vector_type(4))) u32 u32x4;

#define DEV __device__ __forceinline__

DEV u16 f2bf(float f) {
  u32 u = __builtin_bit_cast(u32, f);
  u = (u + 0x7FFFu + ((u >> 16) & 1u)) >> 16;
  return (u16)u;
}

DEV float fexp2(float x) {
#if __has_builtin(__builtin_amdgcn_exp2f)
  return __builtin_amdgcn_exp2f(x);
#else
  return exp2f(x);
#endif
}

DEV u32 cvt_pk_bf16(float lo, float hi) {
  u32 r;
  asm("v_cvt_pk_bf16_f32 %0, %1, %2" : "=v"(r) : "v"(lo), "v"(hi));
  return r;
}

// async global->LDS, 16B per lane; lds base must be wave-uniform.
DEV void llds16(const void* g, void* lds) {
  __builtin_amdgcn_global_load_lds(
      (const __attribute__((address_space(1))) u32*)g,
      (__attribute__((address_space(3))) u32*)lds, 16, 0, 0);
}

// ---------------- fused f32 -> bf16 conversion for all 7 tensors ----------------
struct CvtArgs {
  const float* src[7];
  u16* dst[7];
};

// chunks of 131072 8-elem groups: acts are 4 chunks each (0-11), weights 1 chunk (12-15)
__global__ void cvt_all(CvtArgs ca) {
  int i = blockIdx.x * blockDim.x + threadIdx.x;  // 8-elem group index, 0..2097151
  int chunk = i >> 17;
  int seg = chunk < 12 ? (chunk >> 2) : (chunk - 9);
  u32 base8 = (seg < 3) ? (u32)seg * 524288u : 1572864u + ((u32)seg - 3) * 131072u;
  size_t off = ((size_t)i - base8) * 8;
  const f32x4* p = (const f32x4*)(ca.src[seg] + off);
  f32x4 a = p[0], b = p[1];
  short8 o;
  o[0] = (short)f2bf(a[0]); o[1] = (short)f2bf(a[1]);
  o[2] = (short)f2bf(a[2]); o[3] = (short)f2bf(a[3]);
  o[4] = (short)f2bf(b[0]); o[5] = (short)f2bf(b[1]);
  o[6] = (short)f2bf(b[2]); o[7] = (short)f2bf(b[3]);
  *(short8*)(ca.dst[seg] + off) = o;
}

// ---------------- GEMM: C[M,1024] = A[M,1024] @ W[1024,1024]^T + bias ----------------
// 1-D grid, XCD-aware bijective swizzle; bn fastest within an XCD chunk so each
// XCD sweeps one A-panel across all bn while its per-z W (2MB) stays L2-resident.
struct GemmArgs {
  const u16* A[3];
  const u16* W[3];
  const float* bias[3];
  void* C[3];
  float scale[3];
};

template <int BM, int BN, int WAVES_M, int OUT_BF16, int NB_M>
__global__ __launch_bounds__(256, 2) void gemm_bt(GemmArgs ga) {
  constexpr int K = 1024, N = 1024;
  constexpr int WAVES_N = 4 / WAVES_M;
  constexpr int WM = BM / WAVES_M, WN = BN / WAVES_N;
  constexpr int AM = WM / 16, AN = WN / 16;
  constexpr int SEGS = (BM + BN) / 16;  // 1KB staging segments per K-step
  constexpr int PW = SEGS / 4;          // segments per wave

  __shared__ u16 lsA[BM * 32];
  __shared__ u16 lsB[BN * 32];

  // XCD-aware swizzle (grid divisible by 8; bijective)
  const u32 orig = blockIdx.x;
  const u32 nid = (orig & 7u) * (gridDim.x >> 3) + (orig >> 3);
  const int bn = (int)(nid & 7u);
  const int bm = (int)((nid >> 3) % (u32)NB_M);
  const int z = (int)((nid >> 3) / (u32)NB_M);

  const u16* __restrict__ A = ga.A[z];
  const u16* __restrict__ W = ga.W[z];
  const int tid = threadIdx.x;
  const int l = tid & 63, w = tid >> 6;
  const int lg = l >> 4, lr = l & 15;
  const int wm = w / WAVES_N, wn = w % WAVES_N;

  f32x4 acc[AM][AN];
#pragma unroll
  for (int i = 0; i < AM; ++i)
#pragma unroll
    for (int j = 0; j < AN; ++j) acc[i][j] = (f32x4){0.f, 0.f, 0.f, 0.f};

  for (int k0 = 0; k0 < K; k0 += 32) {
    __syncthreads();
#pragma unroll
    for (int i = 0; i < PW; ++i) {
      int s = w * PW + i;  // wave-uniform
      if (s < BM / 16) {
        u32 sb = s * 1024;
        u32 lb = sb + l * 16;
        u32 row = lb >> 6, colS = (lb & 63) >> 1;
        llds16(A + (size_t)(bm * BM + row) * K + k0 + colS, (char*)lsA + sb);
      } else {
        u32 sb = (u32)(s - BM / 16) * 1024;
        u32 lb = sb + l * 16;
        u32 row = lb >> 6, colS = (lb & 63) >> 1;
        llds16(W + (size_t)(bn * BN + row) * K + k0 + colS, (char*)lsB + sb);
      }
    }
    __syncthreads();
    short8 af[AM], bf[AN];
#pragma unroll
    for (int i = 0; i < AM; ++i)
      af[i] = *(const short8*)&lsA[(wm * WM + i * 16 + lr) * 32 + lg * 8];
#pragma unroll
    for (int j = 0; j < AN; ++j)
      bf[j] = *(const short8*)&lsB[(wn * WN + j * 16 + lr) * 32 + lg * 8];
#pragma unroll
    for (int i = 0; i < AM; ++i)
#pragma unroll
      for (int j = 0; j < AN; ++j)
        acc[i][j] = __builtin_amdgcn_mfma_f32_16x16x32_bf16(af[i], bf[j], acc[i][j], 0, 0, 0);
  }

  const float sc = ga.scale[z];
  const float* __restrict__ bias = ga.bias[z];
#pragma unroll
  for (int j = 0; j < AN; ++j) {
    int col = bn * BN + wn * WN + j * 16 + lr;
    float bv = bias[col];
#pragma unroll
    for (int i = 0; i < AM; ++i) {
      int row0 = bm * BM + wm * WM + i * 16 + lg * 4;
#pragma unroll
      for (int r = 0; r < 4; ++r) {
        float v = (acc[i][j][r] + bv) * sc;
        if constexpr (OUT_BF16)
          ((u16*)ga.C[z])[(size_t)(row0 + r) * N + col] = f2bf(v);
        else
          ((float*)ga.C[z])[(size_t)(row0 + r) * N + col] = v;
      }
    }
  }
}

// ---------------- flash attention (2-wave blocks, 4 blocks/CU, P in-register) ----------------
// Q pre-scaled by log2(e)/8. Layouts: [B*S][1024], head h at cols h*64..h*64+63.
// 2 waves x 32 q-rows = 64 q/block; 1024 blocks = 4/CU (16 waves/CU at independent
// phases -> cross-block pipe overlap). Double-buffered K/V, R4-verified schedule.
// After swapped QK^T, lane (lr,lg) holds exp-scores for q-row g*16+lr at keys
// ks*16+lg*4+{0..3}; cvt_pk words ARE the PV B-fragment with key order
// pi(kp) = (kp&32) + ((kp&4)<<2) + ((kp>>3)&3)*4 + (kp&3); V^T stored [d][kp] pi-permuted.
__global__ __launch_bounds__(128, 2) void attn_fwd(
    const u16* __restrict__ Q, const u16* __restrict__ Kp,
    const u16* __restrict__ V, u16* __restrict__ O) {
  constexpr int S = 2048, LD = 1024;
  __shared__ u16 Kt[2][64 * 64];  // [key][d], byte ^= ((key&7)<<4)
  __shared__ u16 Vt[2][64 * 64];  // [d][kp] (kp = pi-slot), byte ^= ((d&7)<<4)
  const int tid = threadIdx.x;
  const int l = tid & 63, w = tid >> 6;  // w in {0,1}
  const int lg = l >> 4, lr = l & 15;

  const u32 orig = blockIdx.x;  // 0..1023
  const u32 nid = (orig & 7u) * 128u + (orig >> 3);
  const int qt = (int)(nid & 31u);
  const int h = (int)((nid >> 5) & 15u);
  const int b = (int)(nid >> 9);

  const size_t base = ((size_t)b * S) * LD + h * 64;
  const int q0 = qt * 64 + w * 32;  // wave's rows: q0 + g*16 + lr

  short8 qf[2][2];
#pragma unroll
  for (int g = 0; g < 2; ++g)
#pragma unroll
    for (int c = 0; c < 2; ++c)
      qf[g][c] = *(const short8*)&Q[base + (size_t)(q0 + g * 16 + lr) * LD + c * 32 + lg * 8];

  f32x4 acc[2][4];
#pragma unroll
  for (int g = 0; g < 2; ++g)
#pragma unroll
    for (int i = 0; i < 4; ++i) acc[g][i] = (f32x4){0.f, 0.f, 0.f, 0.f};
  float lsum[2] = {0.f, 0.f};

  // V-repack: thread (m, tid>>5) writes slot pair kp0=2m, d in [vd0, vd0+16)
  const int m = tid & 31;
  const int kp0 = m * 2;
  const int key0 = ((m & 16) << 1) + ((m & 2) << 3) + (((m >> 2) & 3) << 2) + ((m & 1) << 1);
  const int vd0 = (tid >> 5) * 16;

#define KSTAGE(T, BUF)                                                          \
  {                                                                             \
    _Pragma("unroll") for (int i_ = 0; i_ < 4; ++i_) {                          \
      u32 sb = (u32)(w * 4 + i_) * 1024;                                        \
      u32 lb = sb + l * 16;                                                     \
      u32 key = lb >> 7;                                                        \
      u32 inner = (lb & 127) ^ ((key & 7) << 4);                                \
      llds16(Kp + base + (size_t)((T) * 64 + key) * LD + (inner >> 1),          \
             (char*)Kt[BUF] + sb);                                              \
    }                                                                           \
  }
#define VLOAD(T, VA0, VA1, VB0, VB1)                                            \
  {                                                                             \
    VA0 = *(const short8*)&V[base + (size_t)((T) * 64 + key0) * LD + vd0];      \
    VA1 = *(const short8*)&V[base + (size_t)((T) * 64 + key0) * LD + vd0 + 8];  \
    VB0 = *(const short8*)&V[base + (size_t)((T) * 64 + key0 + 1) * LD + vd0];  \
    VB1 = *(const short8*)&V[base + (size_t)((T) * 64 + key0 + 1) * LD + vd0 + 8]; \
  }
#define VWRITE(BUF, VA0, VA1, VB0, VB1)                                         \
  {                                                                             \
    _Pragma("unroll") for (int jj = 0; jj < 8; ++jj) {                          \
      u32 pv = (u32)(u16)(VA0)[jj] | ((u32)(u16)(VB0)[jj] << 16);               \
      u32 addr = (u32)((vd0 + jj) * 128 + kp0 * 2) ^ ((u32)jj << 4);            \
      *(u32*)((char*)Vt[BUF] + addr) = pv;                                      \
    }                                                                           \
    _Pragma("unroll") for (int jj = 0; jj < 8; ++jj) {                          \
      u32 pv = (u32)(u16)(VA1)[jj] | ((u32)(u16)(VB1)[jj] << 16);               \
      u32 addr = (u32)((vd0 + 8 + jj) * 128 + kp0 * 2) ^ ((u32)jj << 4);        \
      *(u32*)((char*)Vt[BUF] + addr) = pv;                                      \
    }                                                                           \
  }

  // prologue: stage tile 0
  {
    short8 va0, va1, vb0, vb1;
    VLOAD(0, va0, va1, vb0, vb1);
    KSTAGE(0, 0);
    VWRITE(0, va0, va1, vb0, vb1);
  }
  __syncthreads();

  int cur = 0;
  for (int t = 0; t < 32; ++t) {
    // ---- issue next tile's loads (V->regs, K->LDS async) ----
    short8 nva0, nva1, nvb0, nvb1;
    if (t < 31) {
      VLOAD(t + 1, nva0, nva1, nvb0, nvb1);
      KSTAGE(t + 1, cur ^ 1);
    }

    // ---- S^T = K . Q^T : lane owns q-row (g*16+lr), keys ks*16+lg*4+{0..3} ----
    f32x4 sv[2][4];
    __builtin_amdgcn_s_setprio(1);
#pragma unroll
    for (int ks = 0; ks < 4; ++ks) {
      u32 a0 = (u32)(((ks * 16 + lr) * 128 + lg * 16) ^ ((lr & 7) << 4));
      short8 kf0 = *(const short8*)((const char*)Kt[cur] + a0);
      short8 kf1 = *(const short8*)((const char*)Kt[cur] + (a0 ^ 64));
#pragma unroll
      for (int g = 0; g < 2; ++g) {
        f32x4 s = (f32x4){0.f, 0.f, 0.f, 0.f};
        s = __builtin_amdgcn_mfma_f32_16x16x32_bf16(kf0, qf[g][0], s, 0, 0, 0);
        s = __builtin_amdgcn_mfma_f32_16x16x32_bf16(kf1, qf[g][1], s, 0, 0, 0);
        sv[g][ks] = s;
      }
    }
    __builtin_amdgcn_s_setprio(0);

    // ---- softmax (no-max: scores O(1), f32-safe) + pack to bf16 pairs ----
    u32 pk[2][8];
#pragma unroll
    for (int g = 0; g < 2; ++g) {
#pragma unroll
      for (int ks = 0; ks < 4; ++ks) {
        float e0 = fexp2(sv[g][ks][0]), e1 = fexp2(sv[g][ks][1]);
        float e2 = fexp2(sv[g][ks][2]), e3 = fexp2(sv[g][ks][3]);
        lsum[g] += (e0 + e1) + (e2 + e3);
        pk[g][ks * 2 + 0] = cvt_pk_bf16(e0, e1);
        pk[g][ks * 2 + 1] = cvt_pk_bf16(e2, e3);
      }
    }

    // ---- ctx^T += V^T . P^T : A = Vt (pi-ordered kp axis), B = pk words ----
    __builtin_amdgcn_s_setprio(1);
#pragma unroll
    for (int ds = 0; ds < 4; ++ds) {
#pragma unroll
      for (int c = 0; c < 2; ++c) {
        u32 va_ = (u32)(((ds * 16 + lr) * 128 + c * 64 + lg * 16) ^ ((lr & 7) << 4));
        short8 vf = *(const short8*)((const char*)Vt[cur] + va_);
#pragma unroll
        for (int g = 0; g < 2; ++g) {
          u32x4 pc = {pk[g][c * 4 + 0], pk[g][c * 4 + 1], pk[g][c * 4 + 2], pk[g][c * 4 + 3]};
          short8 pf = __builtin_bit_cast(short8, pc);
          acc[g][ds] = __builtin_amdgcn_mfma_f32_16x16x32_bf16(vf, pf, acc[g][ds], 0, 0, 0);
        }
      }
    }
    __builtin_amdgcn_s_setprio(0);

    // ---- write next V tile (write-late: after PV, before barrier) ----
    if (t < 31) VWRITE(cur ^ 1, nva0, nva1, nvb0, nvb1);
    __syncthreads();
    cur ^= 1;
  }

  // row-sums: lanes lg=0..3 hold disjoint key subsets of row lr
#pragma unroll
  for (int g = 0; g < 2; ++g) {
    lsum[g] += __shfl_xor(lsum[g], 16);
    lsum[g] += __shfl_xor(lsum[g], 32);
  }
#pragma unroll
  for (int g = 0; g < 2; ++g) {
    float inv = __builtin_amdgcn_rcpf(lsum[g]);
#pragma unroll
    for (int ds = 0; ds < 4; ++ds) {
      u32x2 ov;
      ov[0] = cvt_pk_bf16(acc[g][ds][0] * inv, acc[g][ds][1] * inv);
      ov[1] = cvt_pk_bf16(acc[g][ds][2] * inv, acc[g][ds][3] * inv);
      *(u32x2*)&O[base + (size_t)(q0 + g * 16 + lr) * LD + ds * 16 + lg * 4] = ov;
    }
  }
#undef KSTAGE
#undef VLOAD
#undef VWRITE
}

// ---------------- launcher ----------------
extern "C" void kernel_launch(void* const* d_in, const int* in_sizes, int n_in,
                              void* d_out, int out_size, void* d_ws, size_t ws_size,
                              hipStream_t stream) {
  constexpr size_t SZ_X = 4096ull * 1024;  // activation elements
  constexpr size_t SZ_W = 1024ull * 1024;  // weight elements
  const float* bq = (const float*)d_in[4];
  const float* bk = (const float*)d_in[6];
  const float* bv = (const float*)d_in[8];
  const float* bo = (const float*)d_in[10];

  char* ws = (char*)d_ws;
  u16* xq = (u16*)ws;
  u16* xk = xq + SZ_X;
  u16* xv = xk + SZ_X;
  u16* wqb = xv + SZ_X;
  u16* wkb = wqb + SZ_W;
  u16* wvb = wkb + SZ_W;
  u16* wob = wvb + SZ_W;
  u16* Qp = wob + SZ_W;
  u16* Kp = Qp + SZ_X;
  u16* Vp = Kp + SZ_X;
  u16* Cx = Vp + SZ_X;  // total ws use: 64 MB

  CvtArgs ca;
  ca.src[0] = (const float*)d_in[0]; ca.dst[0] = xq;
  ca.src[1] = (const float*)d_in[1]; ca.dst[1] = xk;
  ca.src[2] = (const float*)d_in[2]; ca.dst[2] = xv;
  ca.src[3] = (const float*)d_in[3]; ca.dst[3] = wqb;
  ca.src[4] = (const float*)d_in[5]; ca.dst[4] = wkb;
  ca.src[5] = (const float*)d_in[7]; ca.dst[5] = wvb;
  ca.src[6] = (const float*)d_in[9]; ca.dst[6] = wob;
  cvt_all<<<dim3(8192), 256, 0, stream>>>(ca);

  GemmArgs g1;
  g1.A[0] = xq;  g1.A[1] = xk;  g1.A[2] = xv;
  g1.W[0] = wqb; g1.W[1] = wkb; g1.W[2] = wvb;
  g1.bias[0] = bq; g1.bias[1] = bk; g1.bias[2] = bv;
  g1.C[0] = Qp; g1.C[1] = Kp; g1.C[2] = Vp;
  g1.scale[0] = 0.18033688011112042f;  // log2(e)/8 folded into Q
  g1.scale[1] = 1.f; g1.scale[2] = 1.f;
  gemm_bt<128, 128, 2, 1, 32><<<dim3(768), 256, 0, stream>>>(g1);

  attn_fwd<<<dim3(1024), 128, 0, stream>>>(Qp, Kp, Vp, Cx);

  GemmArgs g2 = {};
  g2.A[0] = Cx; g2.W[0] = wob; g2.bias[0] = bo; g2.C[0] = d_out; g2.scale[0] = 1.f;
  gemm_bt<64, 128, 1, 0, 64><<<dim3(512), 256, 0, stream>>>(g2);
}

// Round 13
// 119.121 us; speedup vs baseline: 1.1611x; 1.1611x over previous
//
#include <hip/hip_runtime.h>

typedef unsigned int u32;
typedef unsigned short u16;
typedef __attribute__((ext_vector_type(8))) short short8;
typedef __attribute__((ext_vector_type(4))) float f32x4;
typedef __attribute__((ext_vector_type(2))) u32 u32x2;
typedef __attribute__((ext_vector_type(4))) u32 u32x4;

#define DEV __device__ __forceinline__

DEV u16 f2bf(float f) {
  u32 u = __builtin_bit_cast(u32, f);
  u = (u + 0x7FFFu + ((u >> 16) & 1u)) >> 16;
  return (u16)u;
}

DEV float fexp2(float x) {
#if __has_builtin(__builtin_amdgcn_exp2f)
  return __builtin_amdgcn_exp2f(x);
#else
  return exp2f(x);
#endif
}

DEV u32 cvt_pk_bf16(float lo, float hi) {
  u32 r;
  asm("v_cvt_pk_bf16_f32 %0, %1, %2" : "=v"(r) : "v"(lo), "v"(hi));
  return r;
}

// async global->LDS, 16B per lane; lds base must be wave-uniform.
DEV void llds16(const void* g, void* lds) {
  __builtin_amdgcn_global_load_lds(
      (const __attribute__((address_space(1))) u32*)g,
      (__attribute__((address_space(3))) u32*)lds, 16, 0, 0);
}

// ---------------- f32 -> bf16 conversion, weights only (4 x 1M elems) ----------------
struct CvtW {
  const float* src[4];
  u16* dst[4];
};

__global__ void cvt_w(CvtW cw) {
  int i = blockIdx.x * blockDim.x + threadIdx.x;  // 8-elem group, 0..524287
  int seg = i >> 17;
  size_t off = ((size_t)(i & 131071)) * 8;
  const f32x4* p = (const f32x4*)(cw.src[seg] + off);
  f32x4 a = p[0], b = p[1];
  u32x4 o;
  o[0] = cvt_pk_bf16(a[0], a[1]);
  o[1] = cvt_pk_bf16(a[2], a[3]);
  o[2] = cvt_pk_bf16(b[0], b[1]);
  o[3] = cvt_pk_bf16(b[2], b[3]);
  *(u32x4*)(cw.dst[seg] + off) = o;
}

// ---------------- GEMM: C[M,1024] = A[M,1024] @ W[1024,1024]^T + bias ----------------
// 1-D grid, XCD-aware bijective swizzle; bn fastest within an XCD chunk so each
// XCD sweeps one A-panel across all bn while its per-z W (2MB) stays L2-resident.
// A_F32 (BM=BN=128 only): A is f32 in global; fused f32->bf16 during staging.
// Each lane owns LINEAR LDS slot seg*1024 + l*16 (DMA-identical, conflict-free)
// and decodes its global (row,col) source from it; A-loads for step k+1 are
// issued at step k (prefetch), consumed after barrier+MFMA+W-DMA (~1000 cyc).
struct GemmArgs {
  const void* A[3];
  const u16* W[3];
  const float* bias[3];
  void* C[3];
  float scale[3];
};

template <int BM, int BN, int WAVES_M, int OUT_BF16, int NB_M, int A_F32>
__global__ __launch_bounds__(256, 2) void gemm_bt(GemmArgs ga) {
  constexpr int K = 1024, N = 1024;
  constexpr int WAVES_N = 4 / WAVES_M;
  constexpr int WM = BM / WAVES_M, WN = BN / WAVES_N;
  constexpr int AM = WM / 16, AN = WN / 16;

  __shared__ u16 lsA[BM * 32];
  __shared__ u16 lsB[BN * 32];

  // XCD-aware swizzle (grid divisible by 8; bijective)
  const u32 orig = blockIdx.x;
  const u32 nid = (orig & 7u) * (gridDim.x >> 3) + (orig >> 3);
  const int bn = (int)(nid & 7u);
  const int bm = (int)((nid >> 3) % (u32)NB_M);
  const int z = (int)((nid >> 3) / (u32)NB_M);

  const u16* __restrict__ W = ga.W[z];
  const int tid = threadIdx.x;
  const int l = tid & 63, w = tid >> 6;
  const int lg = l >> 4, lr = l & 15;
  const int wm = w / WAVES_N, wn = w % WAVES_N;

  f32x4 acc[AM][AN];
#pragma unroll
  for (int i = 0; i < AM; ++i)
#pragma unroll
    for (int j = 0; j < AN; ++j) acc[i][j] = (f32x4){0.f, 0.f, 0.f, 0.f};

  if constexpr (A_F32) {
    const float* __restrict__ Af = (const float*)ga.A[z];
    // lane's two linear A slots: lb = (w*2+i)*1024 + l*16
    // decode: row = lb>>6, f32 col = (lb&63)>>1 (8 consecutive f32)
    const u32 lb0 = (u32)(w * 2 + 0) * 1024 + l * 16;
    const u32 lb1 = (u32)(w * 2 + 1) * 1024 + l * 16;
    const float* src0 = Af + (size_t)(bm * BM + (lb0 >> 6)) * K + ((lb0 & 63) >> 1);
    const float* src1 = Af + (size_t)(bm * BM + (lb1 >> 6)) * K + ((lb1 & 63) >> 1);

    f32x4 pa0, pa1, pb0, pb1;
    pa0 = *(const f32x4*)src0; pa1 = *(const f32x4*)(src0 + 4);
    pb0 = *(const f32x4*)src1; pb1 = *(const f32x4*)(src1 + 4);

    for (int k0 = 0; k0 < K; k0 += 32) {
      __syncthreads();
      // W via DMA: 8 segs, 2 per wave
#pragma unroll
      for (int i = 0; i < 2; ++i) {
        u32 sb = (u32)(w * 2 + i) * 1024;
        u32 lbw = sb + l * 16;
        u32 row = lbw >> 6, colS = (lbw & 63) >> 1;
        llds16(W + (size_t)(bn * BN + row) * K + k0 + colS, (char*)lsB + sb);
      }
      // cvt + conflict-free linear writes (this step's prefetched A data)
      {
        u32x4 o;
        o[0] = cvt_pk_bf16(pa0[0], pa0[1]); o[1] = cvt_pk_bf16(pa0[2], pa0[3]);
        o[2] = cvt_pk_bf16(pa1[0], pa1[1]); o[3] = cvt_pk_bf16(pa1[2], pa1[3]);
        *(u32x4*)((char*)lsA + lb0) = o;
        o[0] = cvt_pk_bf16(pb0[0], pb0[1]); o[1] = cvt_pk_bf16(pb0[2], pb0[3]);
        o[2] = cvt_pk_bf16(pb1[0], pb1[1]); o[3] = cvt_pk_bf16(pb1[2], pb1[3]);
        *(u32x4*)((char*)lsA + lb1) = o;
      }
      // prefetch next step's A (consumed after barrier + MFMA + next W-DMA)
      if (k0 + 32 < K) {
        pa0 = *(const f32x4*)(src0 + k0 + 32); pa1 = *(const f32x4*)(src0 + k0 + 36);
        pb0 = *(const f32x4*)(src1 + k0 + 32); pb1 = *(const f32x4*)(src1 + k0 + 36);
      }
      __syncthreads();
      short8 af[AM], bf[AN];
#pragma unroll
      for (int i = 0; i < AM; ++i)
        af[i] = *(const short8*)&lsA[(wm * WM + i * 16 + lr) * 32 + lg * 8];
#pragma unroll
      for (int j = 0; j < AN; ++j)
        bf[j] = *(const short8*)&lsB[(wn * WN + j * 16 + lr) * 32 + lg * 8];
#pragma unroll
      for (int i = 0; i < AM; ++i)
#pragma unroll
        for (int j = 0; j < AN; ++j)
          acc[i][j] = __builtin_amdgcn_mfma_f32_16x16x32_bf16(af[i], bf[j], acc[i][j], 0, 0, 0);
    }
  } else {
    const u16* __restrict__ A = (const u16*)ga.A[z];
    constexpr int SEGS = (BM + BN) / 16;
    constexpr int PW = SEGS / 4;
    for (int k0 = 0; k0 < K; k0 += 32) {
      __syncthreads();
#pragma unroll
      for (int i = 0; i < PW; ++i) {
        int s = w * PW + i;  // wave-uniform
        if (s < BM / 16) {
          u32 sb = s * 1024;
          u32 lb = sb + l * 16;
          u32 row = lb >> 6, colS = (lb & 63) >> 1;
          llds16(A + (size_t)(bm * BM + row) * K + k0 + colS, (char*)lsA + sb);
        } else {
          u32 sb = (u32)(s - BM / 16) * 1024;
          u32 lb = sb + l * 16;
          u32 row = lb >> 6, colS = (lb & 63) >> 1;
          llds16(W + (size_t)(bn * BN + row) * K + k0 + colS, (char*)lsB + sb);
        }
      }
      __syncthreads();
      short8 af[AM], bf[AN];
#pragma unroll
      for (int i = 0; i < AM; ++i)
        af[i] = *(const short8*)&lsA[(wm * WM + i * 16 + lr) * 32 + lg * 8];
#pragma unroll
      for (int j = 0; j < AN; ++j)
        bf[j] = *(const short8*)&lsB[(wn * WN + j * 16 + lr) * 32 + lg * 8];
#pragma unroll
      for (int i = 0; i < AM; ++i)
#pragma unroll
        for (int j = 0; j < AN; ++j)
          acc[i][j] = __builtin_amdgcn_mfma_f32_16x16x32_bf16(af[i], bf[j], acc[i][j], 0, 0, 0);
    }
  }

  const float sc = ga.scale[z];
  const float* __restrict__ bias = ga.bias[z];
#pragma unroll
  for (int j = 0; j < AN; ++j) {
    int col = bn * BN + wn * WN + j * 16 + lr;
    float bv = bias[col];
#pragma unroll
    for (int i = 0; i < AM; ++i) {
      int row0 = bm * BM + wm * WM + i * 16 + lg * 4;
#pragma unroll
      for (int r = 0; r < 4; ++r) {
        float v = (acc[i][j][r] + bv) * sc;
        if constexpr (OUT_BF16)
          ((u16*)ga.C[z])[(size_t)(row0 + r) * N + col] = f2bf(v);
        else
          ((float*)ga.C[z])[(size_t)(row0 + r) * N + col] = v;
      }
    }
  }
}

// ---------------- flash attention (QK-ahead software pipeline, P in-register) ----------------
// Q pre-scaled by log2(e)/8. Layouts: [B*S][1024], head h at cols h*64..h*64+63.
// 4 waves x 32 q-rows = 128 q/block; quad-buffered K/V tiles (R9 structure, 57.2us).
__global__ __launch_bounds__(256, 2) void attn_fwd(
    const u16* __restrict__ Q, const u16* __restrict__ Kp,
    const u16* __restrict__ V, u16* __restrict__ O) {
  constexpr int S = 2048, LD = 1024;
  __shared__ u16 Kt[4][64 * 64];  // [key][d], byte ^= ((key&7)<<4)
  __shared__ u16 Vt[4][64 * 64];  // [d][kp] (kp = pi-slot), byte ^= ((d&7)<<4)
  const int tid = threadIdx.x;
  const int l = tid & 63, w = tid >> 6;
  const int lg = l >> 4, lr = l & 15;

  const u32 orig = blockIdx.x;  // 0..511
  const u32 nid = (orig & 7u) * 64u + (orig >> 3);
  const int qt = (int)(nid & 15u);
  const int h = (int)((nid >> 4) & 15u);
  const int b = (int)(nid >> 8);

  const size_t base = ((size_t)b * S) * LD + h * 64;
  const int q0 = qt * 128 + w * 32;  // wave's rows: q0 + g*16 + lr

  short8 qf[2][2];
#pragma unroll
  for (int g = 0; g < 2; ++g)
#pragma unroll
    for (int c = 0; c < 2; ++c)
      qf[g][c] = *(const short8*)&Q[base + (size_t)(q0 + g * 16 + lr) * LD + c * 32 + lg * 8];

  f32x4 acc[2][4];
#pragma unroll
  for (int g = 0; g < 2; ++g)
#pragma unroll
    for (int i = 0; i < 4; ++i) acc[g][i] = (f32x4){0.f, 0.f, 0.f, 0.f};
  float lsum[2] = {0.f, 0.f};

  // V-repack thread mapping: slot pair kp0=2m holds keys key0, key0+1 (pi-permuted)
  const int m = tid & 31;
  const int kp0 = m * 2;
  const int key0 = ((m & 16) << 1) + ((m & 2) << 3) + (((m >> 2) & 3) << 2) + ((m & 1) << 1);
  const int vd0 = (tid >> 5) * 8;

#define KSTAGE(T)                                                               \
  {                                                                             \
    _Pragma("unroll") for (int i_ = 0; i_ < 2; ++i_) {                          \
      u32 sb = (u32)(w * 2 + i_) * 1024;                                        \
      u32 lb = sb + l * 16;                                                     \
      u32 key = lb >> 7;                                                        \
      u32 inner = (lb & 127) ^ ((key & 7) << 4);                                \
      llds16(Kp + base + (size_t)((T) * 64 + key) * LD + (inner >> 1),          \
             (char*)Kt[(T) & 3] + sb);                                          \
    }                                                                           \
  }
#define VLOAD(T, VA, VB)                                                        \
  {                                                                             \
    VA = *(const short8*)&V[base + (size_t)((T) * 64 + key0) * LD + vd0];       \
    VB = *(const short8*)&V[base + (size_t)((T) * 64 + key0 + 1) * LD + vd0];   \
  }
#define VWRITE(T, VA, VB)                                                       \
  {                                                                             \
    _Pragma("unroll") for (int jj = 0; jj < 8; ++jj) {                          \
      u32 pv = (u32)(u16)(VA)[jj] | ((u32)(u16)(VB)[jj] << 16);                 \
      u32 addr = (u32)((vd0 + jj) * 128 + kp0 * 2) ^ ((u32)jj << 4);            \
      *(u32*)((char*)Vt[(T) & 3] + addr) = pv;                                  \
    }                                                                           \
  }
// QK: S^T = K.Q^T for tile T into SV; lane owns q-row (g*16+lr), keys ks*16+lg*4+{0..3}
#define QK(T, SV)                                                               \
  {                                                                             \
    __builtin_amdgcn_s_setprio(1);                                              \
    _Pragma("unroll") for (int ks = 0; ks < 4; ++ks) {                          \
      u32 a0 = (u32)(((ks * 16 + lr) * 128 + lg * 16) ^ ((lr & 7) << 4));       \
      short8 kf0 = *(const short8*)((const char*)Kt[(T) & 3] + a0);             \
      short8 kf1 = *(const short8*)((const char*)Kt[(T) & 3] + (a0 ^ 64));      \
      _Pragma("unroll") for (int g = 0; g < 2; ++g) {                           \
        f32x4 s_ = (f32x4){0.f, 0.f, 0.f, 0.f};                                 \
        s_ = __builtin_amdgcn_mfma_f32_16x16x32_bf16(kf0, qf[g][0], s_, 0, 0, 0); \
        s_ = __builtin_amdgcn_mfma_f32_16x16x32_bf16(kf1, qf[g][1], s_, 0, 0, 0); \
        SV[g][ks] = s_;                                                         \
      }                                                                         \
    }                                                                           \
    __builtin_amdgcn_s_setprio(0);                                              \
  }
// SM: exp2 + pack SV -> PK, accumulate lsum
#define SM(SV, PK)                                                              \
  {                                                                             \
    _Pragma("unroll") for (int g = 0; g < 2; ++g) {                             \
      _Pragma("unroll") for (int ks = 0; ks < 4; ++ks) {                        \
        float e0 = fexp2(SV[g][ks][0]), e1 = fexp2(SV[g][ks][1]);               \
        float e2 = fexp2(SV[g][ks][2]), e3 = fexp2(SV[g][ks][3]);               \
        lsum[g] += (e0 + e1) + (e2 + e3);                                       \
        PK[g][ks * 2 + 0] = cvt_pk_bf16(e0, e1);                                \
        PK[g][ks * 2 + 1] = cvt_pk_bf16(e2, e3);                                \
      }                                                                         \
    }                                                                           \
  }
// PV: ctx^T += V^T.P^T for tile T (A = Vt pi-ordered, B = PK words)
#define PV(T, PK)                                                               \
  {                                                                             \
    __builtin_amdgcn_s_setprio(1);                                              \
    _Pragma("unroll") for (int ds = 0; ds < 4; ++ds) {                          \
      _Pragma("unroll") for (int c = 0; c < 2; ++c) {                           \
        u32 va_ = (u32)(((ds * 16 + lr) * 128 + c * 64 + lg * 16) ^ ((lr & 7) << 4)); \
        short8 vf = *(const short8*)((const char*)Vt[(T) & 3] + va_);           \
        _Pragma("unroll") for (int g = 0; g < 2; ++g) {                         \
          u32x4 pc = {PK[g][c * 4 + 0], PK[g][c * 4 + 1], PK[g][c * 4 + 2], PK[g][c * 4 + 3]}; \
          short8 pf = __builtin_bit_cast(short8, pc);                           \
          acc[g][ds] = __builtin_amdgcn_mfma_f32_16x16x32_bf16(vf, pf, acc[g][ds], 0, 0, 0); \
        }                                                                       \
      }                                                                         \
    }                                                                           \
    __builtin_amdgcn_s_setprio(0);                                              \
  }
// One pipeline iteration. On entry: SVC = QK(t); Kt[(t+1)&3] resident; Vt[t&3]
// resident; (VCA,VCB) hold V(t+1) values. Produces SVN = QK(t+1), (VNA,VNB) = V(t+2).
#define ITER(t, SVC, SVN, VCA, VCB, VNA, VNB)                                   \
  {                                                                             \
    if ((t) < 30) { VLOAD((t) + 2, VNA, VNB); KSTAGE((t) + 2); }                \
    if ((t) < 31) QK((t) + 1, SVN);                                             \
    u32 pk_[2][8];                                                              \
    SM(SVC, pk_);                                                               \
    if ((t) < 31) VWRITE((t) + 1, VCA, VCB);                                    \
    PV(t, pk_);                                                                 \
    __syncthreads();                                                            \
  }

  f32x4 svA[2][4], svB[2][4];
  short8 vaA, vbA, vaB, vbB;

  // prologue: stage tiles 0,1; VWRITE(0); barrier; QK(0)
  VLOAD(0, vaB, vbB); KSTAGE(0);
  VLOAD(1, vaA, vbA); KSTAGE(1);
  VWRITE(0, vaB, vbB);
  __syncthreads();
  QK(0, svA);

  for (int tt = 0; tt < 16; ++tt) {
    ITER(2 * tt, svA, svB, vaA, vbA, vaB, vbB);
    ITER(2 * tt + 1, svB, svA, vaB, vbB, vaA, vbA);
  }

  // row-sums: lanes lg=0..3 hold disjoint key subsets of row lr
#pragma unroll
  for (int g = 0; g < 2; ++g) {
    lsum[g] += __shfl_xor(lsum[g], 16);
    lsum[g] += __shfl_xor(lsum[g], 32);
  }
#pragma unroll
  for (int g = 0; g < 2; ++g) {
    float inv = __builtin_amdgcn_rcpf(lsum[g]);
#pragma unroll
    for (int ds = 0; ds < 4; ++ds) {
      u32x2 ov;
      ov[0] = cvt_pk_bf16(acc[g][ds][0] * inv, acc[g][ds][1] * inv);
      ov[1] = cvt_pk_bf16(acc[g][ds][2] * inv, acc[g][ds][3] * inv);
      *(u32x2*)&O[base + (size_t)(q0 + g * 16 + lr) * LD + ds * 16 + lg * 4] = ov;
    }
  }
#undef KSTAGE
#undef VLOAD
#undef VWRITE
#undef QK
#undef SM
#undef PV
#undef ITER
}

// ---------------- launcher ----------------
extern "C" void kernel_launch(void* const* d_in, const int* in_sizes, int n_in,
                              void* d_out, int out_size, void* d_ws, size_t ws_size,
                              hipStream_t stream) {
  constexpr size_t SZ_X = 4096ull * 1024;  // activation elements
  constexpr size_t SZ_W = 1024ull * 1024;  // weight elements
  const float* bq = (const float*)d_in[4];
  const float* bk = (const float*)d_in[6];
  const float* bv = (const float*)d_in[8];
  const float* bo = (const float*)d_in[10];

  char* ws = (char*)d_ws;
  u16* wqb = (u16*)ws;
  u16* wkb = wqb + SZ_W;
  u16* wvb = wkb + SZ_W;
  u16* wob = wvb + SZ_W;
  u16* Qp = wob + SZ_W;
  u16* Kp = Qp + SZ_X;
  u16* Vp = Kp + SZ_X;
  u16* Cx = Vp + SZ_X;  // total ws use: 40 MB

  CvtW cw;
  cw.src[0] = (const float*)d_in[3]; cw.dst[0] = wqb;
  cw.src[1] = (const float*)d_in[5]; cw.dst[1] = wkb;
  cw.src[2] = (const float*)d_in[7]; cw.dst[2] = wvb;
  cw.src[3] = (const float*)d_in[9]; cw.dst[3] = wob;
  cvt_w<<<dim3(2048), 256, 0, stream>>>(cw);

  GemmArgs g1;
  g1.A[0] = d_in[0]; g1.A[1] = d_in[1]; g1.A[2] = d_in[2];  // f32 activations
  g1.W[0] = wqb; g1.W[1] = wkb; g1.W[2] = wvb;
  g1.bias[0] = bq; g1.bias[1] = bk; g1.bias[2] = bv;
  g1.C[0] = Qp; g1.C[1] = Kp; g1.C[2] = Vp;
  g1.scale[0] = 0.18033688011112042f;  // log2(e)/8 folded into Q
  g1.scale[1] = 1.f; g1.scale[2] = 1.f;
  gemm_bt<128, 128, 2, 1, 32, 1><<<dim3(768), 256, 0, stream>>>(g1);

  attn_fwd<<<dim3(512), 256, 0, stream>>>(Qp, Kp, Vp, Cx);

  GemmArgs g2 = {};
  g2.A[0] = Cx; g2.W[0] = wob; g2.bias[0] = bo; g2.C[0] = d_out; g2.scale[0] = 1.f;
  gemm_bt<64, 128, 1, 0, 64, 0><<<dim3(512), 256, 0, stream>>>(g2);
}